// Round 10
// baseline (436.457 us; speedup 1.0000x reference)
//
#include <hip/hip_runtime.h>
#include <hip/hip_bf16.h>
#include <cstdint>
#include <cstddef>
#include <type_traits>

typedef __attribute__((ext_vector_type(8))) short short8;
typedef __attribute__((ext_vector_type(4))) float f32x4;
typedef __attribute__((ext_vector_type(4))) unsigned short us4;

#define DEVINL __device__ __forceinline__

static constexpr int SS_ = 3;
static constexpr int HH = 56, WW = 56;
#define SCALE_Q 0.17677669529663689f   // 32^-0.5

DEVINL unsigned short f2b(float f) {
    unsigned int u = __builtin_bit_cast(unsigned int, f);
    unsigned int r = (u + 0x7FFFu + ((u >> 16) & 1u)) >> 16;
    return (unsigned short)r;
}
DEVINL float b2f(unsigned short s) {
    return __builtin_bit_cast(float, ((unsigned int)s) << 16);
}

// GELU with 3-term A&S 7.1.25 erf (|eps|<=2.5e-5 -> gelu abs err ~1e-4)
DEVINL float gelu(float v) {
    float ax = fabsf(v) * 0.70710678118654752f;
    float t = 1.0f / (1.0f + 0.47047f * ax);
    float poly = t * (0.3480242f + t * (-0.0958798f + t * 0.7478556f));
    float erfv = 1.0f - poly * __expf(-ax * ax);
    erfv = v >= 0.0f ? erfv : -erfv;
    return 0.5f * v * (1.0f + erfv);
}

// async global->LDS, 16B per lane. LDS dest must be wave-uniform base + lane*16.
DEVINL void gload_lds16(const unsigned short* g, unsigned short* l) {
    __builtin_amdgcn_global_load_lds(
        (const __attribute__((address_space(1))) unsigned int*)g,
        (__attribute__((address_space(3))) unsigned int*)l, 16, 0, 0);
}

// ---------------- weight convert + transpose: out[n][k] = bf16(in[k][n]) ----
__global__ void wconv_kernel(const float* __restrict__ in,
                             unsigned short* __restrict__ out, int K, int N) {
    int i = blockIdx.x * 256 + threadIdx.x;
    if (i >= K * N) return;
    int k = i / N, n = i - k * N;
    out[(size_t)n * K + k] = f2b(in[i]);
}

// ---------------- LayerNorm (one wave per token), optional window gather ----
template <int MODE, typename TIN>
__global__ __launch_bounds__(256) void ln_kernel(
    const TIN* __restrict__ x, const float* __restrict__ g,
    const float* __restrict__ be, unsigned short* __restrict__ out) {
    const int wid = threadIdx.x >> 6, lane = threadIdx.x & 63;
    const int t = blockIdx.x * 4 + wid;
    int src;
    if constexpr (MODE == 1) {
        int w = t / 49, p = t - w * 49;
        int b = w >> 6, widx = w & 63;
        int wy = widx >> 3, wx = widx & 7;
        int py = p / 7, px = p - py * 7;
        int y = wy * 7 + py + SS_;  if (y >= HH) y -= HH;
        int xx = wx * 7 + px + SS_; if (xx >= WW) xx -= WW;
        src = b * (HH * WW) + y * WW + xx;
    } else {
        src = t;
    }
    float4 v;
    if constexpr (std::is_same_v<TIN, float>) {
        v = reinterpret_cast<const float4*>(x + (size_t)src * 256)[lane];
    } else {
        us4 u = reinterpret_cast<const us4*>(x + (size_t)src * 256)[lane];
        v.x = b2f(u.x); v.y = b2f(u.y); v.z = b2f(u.z); v.w = b2f(u.w);
    }
    float s = v.x + v.y + v.z + v.w;
    float q = v.x * v.x + v.y * v.y + v.z * v.z + v.w * v.w;
#pragma unroll
    for (int m = 1; m < 64; m <<= 1) {
        s += __shfl_xor(s, m);
        q += __shfl_xor(q, m);
    }
    float mean = s * (1.0f / 256.0f);
    float var = q * (1.0f / 256.0f) - mean * mean;
    float rs = rsqrtf(var + 1e-5f);
    int c = lane * 4;
    us4 o;
    o.x = f2b((v.x - mean) * rs * g[c + 0] + be[c + 0]);
    o.y = f2b((v.y - mean) * rs * g[c + 1] + be[c + 1]);
    o.z = f2b((v.z - mean) * rs * g[c + 2] + be[c + 2]);
    o.w = f2b((v.w - mean) * rs * g[c + 3] + be[c + 3]);
    *reinterpret_cast<us4*>(out + (size_t)t * 256 + c) = o;
}

// ---------------- GEMM: C[M,N] = A[M,K] @ Bt[N,K]^T + bias, epilogues -------
// R7 body (proven): 128x128, BK=64, 4 waves, single-buffer 32KB LDS,
// XCD-chunk swizzle, pre-swizzled global_load_lds, swizzled ds_read_b128.
// EPI 0: qkv scatter.  EPI 1: proj + window-reverse + residual(fp32) -> bf16.
template <int KDIM, int EPI>
__global__ __launch_bounds__(256, 4) void gemm_kernel(
    const unsigned short* __restrict__ A, const unsigned short* __restrict__ Bt,
    const float* __restrict__ bias, void* __restrict__ out0,
    const void* __restrict__ res, unsigned short* __restrict__ o_q,
    unsigned short* __restrict__ o_k, unsigned short* __restrict__ o_v) {
    constexpr int BM = 128, BN = 128, BK = 64;
    __shared__ __align__(16) unsigned short As[BM * BK];
    __shared__ __align__(16) unsigned short Bs[BN * BK];
    const int tid = threadIdx.x;
    const int wid = tid >> 6, lane = tid & 63;

    const int nwg = gridDim.x * gridDim.y;
    const int bid = blockIdx.x + gridDim.x * blockIdx.y;
    const int nb = (bid & 7) * (nwg >> 3) + (bid >> 3);
    const int n0 = (nb % gridDim.x) * BN;
    const int m0 = (nb / gridDim.x) * BM;

    const int wm = wid >> 1, wn = wid & 1;
    const int lr = lane & 15, kg = lane >> 4;
    f32x4 acc[4][4] = {};

    const int srow = tid >> 3;
    const int spos = tid & 7;

    for (int kt = 0; kt < KDIM; kt += BK) {
#pragma unroll
        for (int i = 0; i < 4; i++) {
            int row = i * 32 + srow;
            gload_lds16(A + (size_t)(m0 + row) * KDIM + kt + ((spos ^ (row & 7)) << 3),
                        As + i * 2048 + tid * 8);
        }
#pragma unroll
        for (int i = 0; i < 4; i++) {
            int row = i * 32 + srow;
            gload_lds16(Bt + (size_t)(n0 + row) * KDIM + kt + ((spos ^ (row & 7)) << 3),
                        Bs + i * 2048 + tid * 8);
        }
        __syncthreads();
#pragma unroll
        for (int ks = 0; ks < 2; ks++) {
            short8 a[4], b[4];
#pragma unroll
            for (int mf = 0; mf < 4; mf++) {
                int r = wm * 64 + mf * 16 + lr;
                a[mf] = *reinterpret_cast<const short8*>(
                    As + r * 64 + (((ks * 4 + kg) ^ (r & 7)) << 3));
            }
#pragma unroll
            for (int nf = 0; nf < 4; nf++) {
                int r = wn * 64 + nf * 16 + lr;
                b[nf] = *reinterpret_cast<const short8*>(
                    Bs + r * 64 + (((ks * 4 + kg) ^ (r & 7)) << 3));
            }
#pragma unroll
            for (int mf = 0; mf < 4; mf++)
#pragma unroll
                for (int nf = 0; nf < 4; nf++)
                    acc[mf][nf] = __builtin_amdgcn_mfma_f32_16x16x32_bf16(
                        a[mf], b[nf], acc[mf][nf], 0, 0, 0);
        }
        __syncthreads();
    }

#pragma unroll
    for (int mf = 0; mf < 4; mf++) {
#pragma unroll
        for (int nf = 0; nf < 4; nf++) {
#pragma unroll
            for (int j = 0; j < 4; j++) {
                int row = m0 + wm * 64 + mf * 16 + kg * 4 + j;
                int col = n0 + wn * 64 + nf * 16 + lr;
                float v = acc[mf][nf][j] + bias[col];
                if constexpr (EPI == 0) {
                    int w = row / 49, p = row - w * 49;
                    int which = col >> 8, h = (col >> 5) & 7, d = col & 31;
                    size_t th = (size_t)(w * 8 + h);
                    if (which == 0)
                        o_q[th * 1568 + p * 32 + d] = f2b(v * SCALE_Q);
                    else if (which == 1)
                        o_k[th * 1568 + p * 32 + d] = f2b(v);
                    else
                        o_v[th * 2048 + d * 64 + p] = f2b(v);
                } else {
                    int w = row / 49, p = row - w * 49;
                    int b2 = w >> 6, widx = w & 63;
                    int wy = widx >> 3, wx = widx & 7;
                    int py = p / 7, px = p - py * 7;
                    int y = wy * 7 + py + SS_;  if (y >= HH) y -= HH;
                    int xx = wx * 7 + px + SS_; if (xx >= WW) xx -= WW;
                    size_t oi = ((size_t)(b2 * 3136 + y * 56 + xx)) * 256 + col;
                    reinterpret_cast<unsigned short*>(out0)[oi] =
                        f2b(v + reinterpret_cast<const float*>(res)[oi]);
                }
            }
        }
    }
}

// ---------------- fused FC1 + GELU + FC2 (a1 stays in LDS) -----------------
// Per block: 64 rows. Phase 1: a1[64][1024] = gelu(h2 @ W1 + b1) into a
// 128KB XOR-swizzled LDS tile. Swapped MFMA (mfma(w1,h2)) -> lane lr = m-row,
// regs j = 4 consecutive n -> us4 LDS writes (R8 HW-verified layout).
// Operand frags gathered directly from L2 (weights 0.5MB stay hot; no
// staging, no per-step barriers -> compiler pipelines freely).
// One __syncthreads. Phase 2: out = a1 @ W2 + b2 + res; a1 frags via
// swizzled ds_read_b128 (2-way conflict = free), W2 frags from L2.
// Eliminates the 205MB a1 HBM round-trip of the split FC1/FC2 kernels.
__global__ __launch_bounds__(512) void fc_fused_kernel(
    const unsigned short* __restrict__ h2,    // [50176][256] bf16
    const unsigned short* __restrict__ w1t,   // [1024][256] bf16 (n-major)
    const float* __restrict__ b1,             // [1024]
    const unsigned short* __restrict__ w2t,   // [256][1024] bf16 (n-major)
    const float* __restrict__ b2,             // [256]
    const unsigned short* __restrict__ res,   // x2b [50176][256] bf16
    float* __restrict__ out) {                // [50176][256] fp32
    __shared__ __align__(16) unsigned short a1s[64 * 1024];  // 128 KiB
    const int tid = threadIdx.x;
    const int wid = tid >> 6, lane = tid & 63;
    const int lr = lane & 15, kg = lane >> 4;
    const int m0 = blockIdx.x * 64;

    // ---------------- phase 1 ----------------
#pragma unroll 1
    for (int p = 0; p < 2; p++) {
        const int nbase = wid * 128 + p * 64;
        f32x4 acc[4][4] = {};
#pragma unroll
        for (int ks = 0; ks < 8; ks++) {
            short8 hf[4], wf[4];
#pragma unroll
            for (int mf = 0; mf < 4; mf++)
                hf[mf] = *reinterpret_cast<const short8*>(
                    h2 + (size_t)(m0 + mf * 16 + lr) * 256 + ks * 32 + kg * 8);
#pragma unroll
            for (int nf = 0; nf < 4; nf++)
                wf[nf] = *reinterpret_cast<const short8*>(
                    w1t + (size_t)(nbase + nf * 16 + lr) * 256 + ks * 32 + kg * 8);
#pragma unroll
            for (int mf = 0; mf < 4; mf++)
#pragma unroll
                for (int nf = 0; nf < 4; nf++)
                    acc[mf][nf] = __builtin_amdgcn_mfma_f32_16x16x32_bf16(
                        wf[nf], hf[mf], acc[mf][nf], 0, 0, 0);  // swapped
        }
        // gelu + bias -> us4 writes into swizzled a1s
#pragma unroll
        for (int nf = 0; nf < 4; nf++) {
            const int ncol = nbase + nf * 16 + kg * 4;   // 4 consecutive n
            const float4 bq = *reinterpret_cast<const float4*>(b1 + ncol);
            const int c8 = ncol >> 3, woff = ncol & 7;
#pragma unroll
            for (int mf = 0; mf < 4; mf++) {
                const int row = mf * 16 + lr;
                us4 o;
                o.x = f2b(gelu(acc[mf][nf][0] + bq.x));
                o.y = f2b(gelu(acc[mf][nf][1] + bq.y));
                o.z = f2b(gelu(acc[mf][nf][2] + bq.z));
                o.w = f2b(gelu(acc[mf][nf][3] + bq.w));
                *reinterpret_cast<us4*>(
                    a1s + row * 1024 + ((c8 ^ (row & 7)) << 3) + woff) = o;
            }
        }
    }
    __syncthreads();

    // ---------------- phase 2 ----------------
    const int wm2 = wid >> 2, wn2 = wid & 3;   // rows wm2*32, cols wn2*64
    f32x4 acc2[2][4] = {};
#pragma unroll 4
    for (int kt = 0; kt < 32; kt++) {
        short8 af[2], bf[4];
#pragma unroll
        for (int mf = 0; mf < 2; mf++) {
            const int m = wm2 * 32 + mf * 16 + lr;
            af[mf] = *reinterpret_cast<const short8*>(
                a1s + m * 1024 + (((kt * 4 + kg) ^ (m & 7)) << 3));
        }
#pragma unroll
        for (int nf = 0; nf < 4; nf++)
            bf[nf] = *reinterpret_cast<const short8*>(
                w2t + (size_t)(wn2 * 64 + nf * 16 + lr) * 1024 + kt * 32 + kg * 8);
#pragma unroll
        for (int mf = 0; mf < 2; mf++)
#pragma unroll
            for (int nf = 0; nf < 4; nf++)
                acc2[mf][nf] = __builtin_amdgcn_mfma_f32_16x16x32_bf16(
                    af[mf], bf[nf], acc2[mf][nf], 0, 0, 0);
    }
#pragma unroll
    for (int nf = 0; nf < 4; nf++) {
        const int col = wn2 * 64 + nf * 16 + lr;
        const float bb = b2[col];
#pragma unroll
        for (int mf = 0; mf < 2; mf++) {
#pragma unroll
            for (int j = 0; j < 4; j++) {
                const int row = m0 + wm2 * 32 + mf * 16 + kg * 4 + j;
                const size_t oi = (size_t)row * 256 + col;
                out[oi] = acc2[mf][nf][j] + bb + b2f(res[oi]);
            }
        }
    }
}

// ---------------- fused window attention: one wave per (window, head) -------
__global__ __launch_bounds__(256) void attn_kernel(
    const unsigned short* __restrict__ qg, const unsigned short* __restrict__ kgl,
    const unsigned short* __restrict__ vg, const float* __restrict__ rpt,
    unsigned short* __restrict__ out) {
    __shared__ __align__(16) unsigned short sm[4][6144];
    __shared__ unsigned short rpts[169 * 8];
    const int tid = threadIdx.x, wid = tid >> 6, lane = tid & 63;
    for (int i = tid; i < 169 * 8; i += 256) rpts[i] = f2b(rpt[i]);
    const int task = blockIdx.x * 4 + wid;
    const int w = task >> 3, h = task & 7;
    const int widx = w & 63, wy = widx >> 3, wx = widx & 7;
    unsigned short* q_s = sm[wid];
    unsigned short* k_s = sm[wid] + 2048;
    unsigned short* v_s = sm[wid] + 4096;
    unsigned short* p_s = sm[wid];
    const unsigned short* qsrc = qg + (size_t)task * 1568;
    const unsigned short* ksrc = kgl + (size_t)task * 1568;
    const unsigned short* vsrc = vg + (size_t)task * 2048;
    for (int c = lane; c < 196; c += 64) {
        int row = c >> 2, kc = c & 3;
        int off = (row * 32 + kc * 8) ^ ((row & 7) << 3);
        *reinterpret_cast<short8*>(q_s + off) =
            *reinterpret_cast<const short8*>(qsrc + c * 8);
        *reinterpret_cast<short8*>(k_s + off) =
            *reinterpret_cast<const short8*>(ksrc + c * 8);
    }
#pragma unroll
    for (int i = 0; i < 4; i++) {
        int c = i * 64 + lane;
        int row = c >> 3, kc = c & 7;
        int off = (row * 64 + kc * 8) ^ ((row & 7) << 3);
        *reinterpret_cast<short8*>(v_s + off) =
            *reinterpret_cast<const short8*>(vsrc + c * 8);
    }
    __syncthreads();

    const int lr = lane & 15, kg = lane >> 4;
    short8 af[4], bf[4];
#pragma unroll
    for (int mf = 0; mf < 4; mf++) {
        int r = mf * 16 + lr;
        af[mf] = *reinterpret_cast<const short8*>(
            q_s + ((r * 32 + kg * 8) ^ ((r & 7) << 3)));
    }
#pragma unroll
    for (int nf = 0; nf < 4; nf++) {
        int r = nf * 16 + lr;
        bf[nf] = *reinterpret_cast<const short8*>(
            k_s + ((r * 32 + kg * 8) ^ ((r & 7) << 3)));
    }
    f32x4 s[4][4] = {};
#pragma unroll
    for (int mf = 0; mf < 4; mf++)
#pragma unroll
        for (int nf = 0; nf < 4; nf++)
            s[mf][nf] = __builtin_amdgcn_mfma_f32_16x16x32_bf16(af[mf], bf[nf],
                                                                s[mf][nf], 0, 0, 0);
#pragma unroll
    for (int mf = 0; mf < 4; mf++) {
#pragma unroll
        for (int j = 0; j < 4; j++) {
            int row = mf * 16 + kg * 4 + j;
            bool rvalid = row < 49;
            int qy = 0, qx = 0, gq = 0;
            if (rvalid) {
                qy = row / 7; qx = row - qy * 7;
                int yi = wy * 7 + qy, xi = wx * 7 + qx;
                gq = ((yi < 49) ? 0 : ((yi < 53) ? 1 : 2)) * 3 +
                     ((xi < 49) ? 0 : ((xi < 53) ? 1 : 2));
            }
            float L[4];
#pragma unroll
            for (int nf = 0; nf < 4; nf++) {
                int col = nf * 16 + lr;
                float val = s[mf][nf][j];
                if (rvalid && col < 49) {
                    int ky = col / 7, kx = col - ky * 7;
                    int yi = wy * 7 + ky, xi = wx * 7 + kx;
                    int gk = ((yi < 49) ? 0 : ((yi < 53) ? 1 : 2)) * 3 +
                             ((xi < 49) ? 0 : ((xi < 53) ? 1 : 2));
                    val += b2f(rpts[((qy - ky + 6) * 13 + (qx - kx + 6)) * 8 + h]);
                    if (gq != gk) val -= 100.0f;
                } else {
                    val = -1e30f;
                }
                L[nf] = val;
            }
            float m = fmaxf(fmaxf(L[0], L[1]), fmaxf(L[2], L[3]));
#pragma unroll
            for (int t2 = 1; t2 < 16; t2 <<= 1) m = fmaxf(m, __shfl_xor(m, t2));
            float P[4], psum = 0.f;
#pragma unroll
            for (int nf = 0; nf < 4; nf++) {
                P[nf] = __expf(L[nf] - m);
                psum += P[nf];
            }
#pragma unroll
            for (int t2 = 1; t2 < 16; t2 <<= 1) psum += __shfl_xor(psum, t2);
            float inv = 1.0f / psum;
#pragma unroll
            for (int nf = 0; nf < 4; nf++) {
                int col = nf * 16 + lr;
                p_s[(row * 64 + col) ^ ((row & 7) << 3)] = f2b(P[nf] * inv);
            }
        }
    }
    f32x4 o[4][2] = {};
#pragma unroll
    for (int ks = 0; ks < 2; ks++) {
        short8 pa[4], vb[2];
#pragma unroll
        for (int mf = 0; mf < 4; mf++) {
            int r = mf * 16 + lr;
            pa[mf] = *reinterpret_cast<const short8*>(
                p_s + ((r * 64 + ks * 32 + kg * 8) ^ ((r & 7) << 3)));
        }
#pragma unroll
        for (int nf = 0; nf < 2; nf++) {
            int d = nf * 16 + lr;
            vb[nf] = *reinterpret_cast<const short8*>(
                v_s + ((d * 64 + ks * 32 + kg * 8) ^ ((d & 7) << 3)));
        }
#pragma unroll
        for (int mf = 0; mf < 4; mf++)
#pragma unroll
            for (int nf = 0; nf < 2; nf++)
                o[mf][nf] = __builtin_amdgcn_mfma_f32_16x16x32_bf16(
                    pa[mf], vb[nf], o[mf][nf], 0, 0, 0);
    }
#pragma unroll
    for (int mf = 0; mf < 4; mf++) {
#pragma unroll
        for (int j = 0; j < 4; j++) {
            int row = mf * 16 + kg * 4 + j;
            if (row < 49) {
#pragma unroll
                for (int nf = 0; nf < 2; nf++) {
                    int d = nf * 16 + lr;
                    out[((size_t)w * 49 + row) * 256 + h * 32 + d] =
                        f2b(o[mf][nf][j]);
                }
            }
        }
    }
}

// ---------------- launcher --------------------------------------------------
extern "C" void kernel_launch(void* const* d_in, const int* in_sizes, int n_in,
                              void* d_out, int out_size, void* d_ws,
                              size_t ws_size, hipStream_t stream) {
    const float* x     = (const float*)d_in[0];
    const float* g1    = (const float*)d_in[1];
    const float* be1   = (const float*)d_in[2];
    const float* wqkv  = (const float*)d_in[3];
    const float* bqkv  = (const float*)d_in[4];
    const float* rpt   = (const float*)d_in[5];
    const float* wproj = (const float*)d_in[6];
    const float* bproj = (const float*)d_in[7];
    const float* g2    = (const float*)d_in[8];
    const float* be2   = (const float*)d_in[9];
    const float* wfc1  = (const float*)d_in[10];
    const float* bfc1  = (const float*)d_in[11];
    const float* wfc2  = (const float*)d_in[12];
    const float* bfc2  = (const float*)d_in[13];
    float* out = (float*)d_out;
    char* ws = (char*)d_ws;

    unsigned short* hb  = (unsigned short*)(ws);              // 25,690,112 B
    unsigned short* qg  = (unsigned short*)(ws + 25690112);   // 25,690,112
    unsigned short* kgl = (unsigned short*)(ws + 51380224);   // 25,690,112
    unsigned short* vg  = (unsigned short*)(ws + 77070336);   // 33,554,432
    unsigned short* x2b = (unsigned short*)(ws + 110624768);  // 25,690,112 (bf16)
    unsigned short* h2  = (unsigned short*)(ws + 162004992);  // 25,690,112
    unsigned short* wT  = (unsigned short*)(ws + 187695104);  // 1,572,864
    unsigned short* wqkvT = wT;
    unsigned short* wprojT = wT + 196608;
    unsigned short* wfc1T  = wT + 262144;
    unsigned short* wfc2T  = wT + 524288;

    wconv_kernel<<<(256 * 768 + 255) / 256, 256, 0, stream>>>(wqkv, wqkvT, 256, 768);
    wconv_kernel<<<(256 * 256 + 255) / 256, 256, 0, stream>>>(wproj, wprojT, 256, 256);
    wconv_kernel<<<(256 * 1024 + 255) / 256, 256, 0, stream>>>(wfc1, wfc1T, 256, 1024);
    wconv_kernel<<<(1024 * 256 + 255) / 256, 256, 0, stream>>>(wfc2, wfc2T, 1024, 256);
    // no v-pad memset: pad cols (p>=49) multiply by exactly-zero P; 0xAA bf16
    // poison and stale bf16 values are always finite.

    ln_kernel<1, float><<<12544, 256, 0, stream>>>(x, g1, be1, hb);
    gemm_kernel<256, 0><<<dim3(6, 392), 256, 0, stream>>>(
        hb, wqkvT, bqkv, nullptr, nullptr, qg, kgl, vg);
    attn_kernel<<<2048, 256, 0, stream>>>(qg, kgl, vg, rpt, hb);
    gemm_kernel<256, 1><<<dim3(2, 392), 256, 0, stream>>>(
        hb, wprojT, bproj, x2b, x, nullptr, nullptr, nullptr);
    ln_kernel<0, unsigned short><<<12544, 256, 0, stream>>>(x2b, g2, be2, h2);
    fc_fused_kernel<<<784, 512, 0, stream>>>(
        h2, wfc1T, bfc1, wfc2T, bfc2, x2b, out);
}

// Round 11
// 322.185 us; speedup vs baseline: 1.3547x; 1.3547x over previous
//
#include <hip/hip_runtime.h>
#include <hip/hip_bf16.h>
#include <cstdint>
#include <cstddef>
#include <type_traits>

typedef __attribute__((ext_vector_type(8))) short short8;
typedef __attribute__((ext_vector_type(4))) float f32x4;
typedef __attribute__((ext_vector_type(4))) unsigned short us4;

#define DEVINL __device__ __forceinline__

static constexpr int SS_ = 3;
static constexpr int HH = 56, WW = 56;
#define SCALE_Q 0.17677669529663689f   // 32^-0.5

DEVINL unsigned short f2b(float f) {
    unsigned int u = __builtin_bit_cast(unsigned int, f);
    unsigned int r = (u + 0x7FFFu + ((u >> 16) & 1u)) >> 16;
    return (unsigned short)r;
}
DEVINL float b2f(unsigned short s) {
    return __builtin_bit_cast(float, ((unsigned int)s) << 16);
}

// GELU with 3-term A&S 7.1.25 erf (|eps|<=2.5e-5 -> gelu abs err ~1e-4)
DEVINL float gelu(float v) {
    float ax = fabsf(v) * 0.70710678118654752f;
    float t = 1.0f / (1.0f + 0.47047f * ax);
    float poly = t * (0.3480242f + t * (-0.0958798f + t * 0.7478556f));
    float erfv = 1.0f - poly * __expf(-ax * ax);
    erfv = v >= 0.0f ? erfv : -erfv;
    return 0.5f * v * (1.0f + erfv);
}

// async global->LDS, 16B per lane. LDS dest must be wave-uniform base + lane*16.
DEVINL void gload_lds16(const unsigned short* g, unsigned short* l) {
    __builtin_amdgcn_global_load_lds(
        (const __attribute__((address_space(1))) unsigned int*)g,
        (__attribute__((address_space(3))) unsigned int*)l, 16, 0, 0);
}

// ---------------- weight convert + transpose: out[n][k] = bf16(in[k][n]) ----
__global__ void wconv_kernel(const float* __restrict__ in,
                             unsigned short* __restrict__ out, int K, int N) {
    int i = blockIdx.x * 256 + threadIdx.x;
    if (i >= K * N) return;
    int k = i / N, n = i - k * N;
    out[(size_t)n * K + k] = f2b(in[i]);
}

// ---------------- LayerNorm (one wave per token), optional window gather ----
template <int MODE, typename TIN>
__global__ __launch_bounds__(256) void ln_kernel(
    const TIN* __restrict__ x, const float* __restrict__ g,
    const float* __restrict__ be, unsigned short* __restrict__ out) {
    const int wid = threadIdx.x >> 6, lane = threadIdx.x & 63;
    const int t = blockIdx.x * 4 + wid;
    int src;
    if constexpr (MODE == 1) {
        int w = t / 49, p = t - w * 49;
        int b = w >> 6, widx = w & 63;
        int wy = widx >> 3, wx = widx & 7;
        int py = p / 7, px = p - py * 7;
        int y = wy * 7 + py + SS_;  if (y >= HH) y -= HH;
        int xx = wx * 7 + px + SS_; if (xx >= WW) xx -= WW;
        src = b * (HH * WW) + y * WW + xx;
    } else {
        src = t;
    }
    float4 v;
    if constexpr (std::is_same_v<TIN, float>) {
        v = reinterpret_cast<const float4*>(x + (size_t)src * 256)[lane];
    } else {
        us4 u = reinterpret_cast<const us4*>(x + (size_t)src * 256)[lane];
        v.x = b2f(u.x); v.y = b2f(u.y); v.z = b2f(u.z); v.w = b2f(u.w);
    }
    float s = v.x + v.y + v.z + v.w;
    float q = v.x * v.x + v.y * v.y + v.z * v.z + v.w * v.w;
#pragma unroll
    for (int m = 1; m < 64; m <<= 1) {
        s += __shfl_xor(s, m);
        q += __shfl_xor(q, m);
    }
    float mean = s * (1.0f / 256.0f);
    float var = q * (1.0f / 256.0f) - mean * mean;
    float rs = rsqrtf(var + 1e-5f);
    int c = lane * 4;
    us4 o;
    o.x = f2b((v.x - mean) * rs * g[c + 0] + be[c + 0]);
    o.y = f2b((v.y - mean) * rs * g[c + 1] + be[c + 1]);
    o.z = f2b((v.z - mean) * rs * g[c + 2] + be[c + 2]);
    o.w = f2b((v.w - mean) * rs * g[c + 3] + be[c + 3]);
    *reinterpret_cast<us4*>(out + (size_t)t * 256 + c) = o;
}

// ---------------- K=256 GEMM, B-panel resident, 4 m-tiles per block --------
// Per block: B panel [128][256] staged ONCE into 64KB LDS (4 swizzled BK=64
// sections); then 4 m-tiles processed serially, staging only A (4 loads/step
// vs 8). At each tile's last K-step the next tile's A-stage is issued BEFORE
// the epilogue, hiding one of four stage-drains under epilogue stores.
// 80KB LDS -> 2 blocks/CU (8 waves/CU = R7's measured residency).
// General bijective XCD-chunk swizzle (m204; grids here aren't all %8==0).
// EPI 0: qkv scatter.  EPI 1: proj + window-reverse + residual(fp32) -> bf16.
// EPI 2: GELU -> bf16.
template <int EPI>
__global__ __launch_bounds__(256, 2) void gemm_k256_kernel(
    const unsigned short* __restrict__ A, const unsigned short* __restrict__ Bt,
    const float* __restrict__ bias, void* __restrict__ out0,
    const void* __restrict__ res, unsigned short* __restrict__ o_q,
    unsigned short* __restrict__ o_k, unsigned short* __restrict__ o_v) {
    __shared__ __align__(16) unsigned short Bs[4][8192];  // 64 KiB
    __shared__ __align__(16) unsigned short As[8192];     // 16 KiB
    const int tid = threadIdx.x;
    const int wid = tid >> 6, lane = tid & 63;

    // bijective XCD-chunk swizzle (m204)
    const int nwg = gridDim.x * gridDim.y;
    const int orig = blockIdx.x + gridDim.x * blockIdx.y;
    const int q8 = nwg >> 3, r8 = nwg & 7;
    const int xcd = orig & 7, idx = orig >> 3;
    const int nb = (xcd < r8 ? xcd * (q8 + 1) : r8 * (q8 + 1) + (xcd - r8) * q8) + idx;
    const int n0 = (nb % gridDim.x) * 128;
    const int mg = nb / gridDim.x;           // group of 4 m-tiles

    const int wm = wid >> 1, wn = wid & 1;
    const int lr = lane & 15, kg = lane >> 4;
    const int srow = tid >> 3, spos = tid & 7;

    auto stageA = [&](int m0, int kt) {
#pragma unroll
        for (int i = 0; i < 4; i++) {
            int row = i * 32 + srow;
            gload_lds16(A + (size_t)(m0 + row) * 256 + kt * 64 +
                            ((spos ^ (row & 7)) << 3),
                        As + i * 2048 + tid * 8);
        }
    };

    // prologue: full B panel + first A tile
#pragma unroll
    for (int kt = 0; kt < 4; kt++)
#pragma unroll
        for (int i = 0; i < 4; i++) {
            int row = i * 32 + srow;
            gload_lds16(Bt + (size_t)(n0 + row) * 256 + kt * 64 +
                            ((spos ^ (row & 7)) << 3),
                        Bs[kt] + i * 2048 + tid * 8);
        }
    stageA(mg * 512, 0);
    __syncthreads();

#pragma unroll 1
    for (int g = 0; g < 4; g++) {
        const int m0 = mg * 512 + g * 128;
        f32x4 acc[4][4] = {};

        auto epilogue = [&]() {
#pragma unroll
            for (int mf = 0; mf < 4; mf++) {
#pragma unroll
                for (int nf = 0; nf < 4; nf++) {
#pragma unroll
                    for (int j = 0; j < 4; j++) {
                        int row = m0 + wm * 64 + mf * 16 + kg * 4 + j;
                        int col = n0 + wn * 64 + nf * 16 + lr;
                        float v = acc[mf][nf][j] + bias[col];
                        if constexpr (EPI == 0) {
                            int w = row / 49, p = row - w * 49;
                            int which = col >> 8, h = (col >> 5) & 7, d = col & 31;
                            size_t th = (size_t)(w * 8 + h);
                            if (which == 0)
                                o_q[th * 1568 + p * 32 + d] = f2b(v * SCALE_Q);
                            else if (which == 1)
                                o_k[th * 1568 + p * 32 + d] = f2b(v);
                            else
                                o_v[th * 2048 + d * 64 + p] = f2b(v);
                        } else if constexpr (EPI == 1) {
                            int w = row / 49, p = row - w * 49;
                            int b2 = w >> 6, widx = w & 63;
                            int wy = widx >> 3, wx = widx & 7;
                            int py = p / 7, px = p - py * 7;
                            int y = wy * 7 + py + SS_;  if (y >= HH) y -= HH;
                            int xx = wx * 7 + px + SS_; if (xx >= WW) xx -= WW;
                            size_t oi = ((size_t)(b2 * 3136 + y * 56 + xx)) * 256 + col;
                            reinterpret_cast<unsigned short*>(out0)[oi] =
                                f2b(v + reinterpret_cast<const float*>(res)[oi]);
                        } else {
                            reinterpret_cast<unsigned short*>(out0)
                                [(size_t)row * 1024 + col] = f2b(gelu(v));
                        }
                    }
                }
            }
        };

#pragma unroll
        for (int kt = 0; kt < 4; kt++) {
#pragma unroll
            for (int ks = 0; ks < 2; ks++) {
                short8 a[4], b[4];
#pragma unroll
                for (int mf = 0; mf < 4; mf++) {
                    int r = wm * 64 + mf * 16 + lr;
                    a[mf] = *reinterpret_cast<const short8*>(
                        As + r * 64 + (((ks * 4 + kg) ^ (r & 7)) << 3));
                }
#pragma unroll
                for (int nf = 0; nf < 4; nf++) {
                    int r = wn * 64 + nf * 16 + lr;
                    b[nf] = *reinterpret_cast<const short8*>(
                        Bs[kt] + r * 64 + (((ks * 4 + kg) ^ (r & 7)) << 3));
                }
#pragma unroll
                for (int mf = 0; mf < 4; mf++)
#pragma unroll
                    for (int nf = 0; nf < 4; nf++)
                        acc[mf][nf] = __builtin_amdgcn_mfma_f32_16x16x32_bf16(
                            a[mf], b[nf], acc[mf][nf], 0, 0, 0);
            }
            __syncthreads();                 // all waves done reading As
            if (kt < 3) {
                stageA(m0, kt + 1);
            } else {
                if (g < 3) stageA(m0 + 128, 0);   // issue next tile's stage...
                epilogue();                        // ...then hide drain under it
            }
            __syncthreads();                 // staged data visible
        }
    }
}

// ---------------- GEMM (R7 body) -- used for FC2 (K=1024) ------------------
template <int KDIM, int EPI>
__global__ __launch_bounds__(256, 4) void gemm_kernel(
    const unsigned short* __restrict__ A, const unsigned short* __restrict__ Bt,
    const float* __restrict__ bias, void* __restrict__ out0,
    const void* __restrict__ res, unsigned short* __restrict__ o_q,
    unsigned short* __restrict__ o_k, unsigned short* __restrict__ o_v) {
    constexpr int BM = 128, BN = 128, BK = 64;
    __shared__ __align__(16) unsigned short As[BM * BK];
    __shared__ __align__(16) unsigned short Bs[BN * BK];
    const int tid = threadIdx.x;
    const int wid = tid >> 6, lane = tid & 63;

    const int nwg = gridDim.x * gridDim.y;
    const int bid = blockIdx.x + gridDim.x * blockIdx.y;
    const int nb = (bid & 7) * (nwg >> 3) + (bid >> 3);
    const int n0 = (nb % gridDim.x) * BN;
    const int m0 = (nb / gridDim.x) * BM;

    const int wm = wid >> 1, wn = wid & 1;
    const int lr = lane & 15, kg = lane >> 4;
    f32x4 acc[4][4] = {};

    const int srow = tid >> 3;
    const int spos = tid & 7;

    for (int kt = 0; kt < KDIM; kt += BK) {
#pragma unroll
        for (int i = 0; i < 4; i++) {
            int row = i * 32 + srow;
            gload_lds16(A + (size_t)(m0 + row) * KDIM + kt + ((spos ^ (row & 7)) << 3),
                        As + i * 2048 + tid * 8);
        }
#pragma unroll
        for (int i = 0; i < 4; i++) {
            int row = i * 32 + srow;
            gload_lds16(Bt + (size_t)(n0 + row) * KDIM + kt + ((spos ^ (row & 7)) << 3),
                        Bs + i * 2048 + tid * 8);
        }
        __syncthreads();
#pragma unroll
        for (int ks = 0; ks < 2; ks++) {
            short8 a[4], b[4];
#pragma unroll
            for (int mf = 0; mf < 4; mf++) {
                int r = wm * 64 + mf * 16 + lr;
                a[mf] = *reinterpret_cast<const short8*>(
                    As + r * 64 + (((ks * 4 + kg) ^ (r & 7)) << 3));
            }
#pragma unroll
            for (int nf = 0; nf < 4; nf++) {
                int r = wn * 64 + nf * 16 + lr;
                b[nf] = *reinterpret_cast<const short8*>(
                    Bs + r * 64 + (((ks * 4 + kg) ^ (r & 7)) << 3));
            }
#pragma unroll
            for (int mf = 0; mf < 4; mf++)
#pragma unroll
                for (int nf = 0; nf < 4; nf++)
                    acc[mf][nf] = __builtin_amdgcn_mfma_f32_16x16x32_bf16(
                        a[mf], b[nf], acc[mf][nf], 0, 0, 0);
        }
        __syncthreads();
    }

#pragma unroll
    for (int mf = 0; mf < 4; mf++) {
#pragma unroll
        for (int nf = 0; nf < 4; nf++) {
#pragma unroll
            for (int j = 0; j < 4; j++) {
                int row = m0 + wm * 64 + mf * 16 + kg * 4 + j;
                int col = n0 + wn * 64 + nf * 16 + lr;
                float v = acc[mf][nf][j] + bias[col];
                size_t oi = (size_t)row * 256 + col;
                reinterpret_cast<float*>(out0)[oi] =
                    v + b2f(reinterpret_cast<const unsigned short*>(res)[oi]);
            }
        }
    }
}

// ---------------- fused window attention: one wave per (window, head) -------
__global__ __launch_bounds__(256) void attn_kernel(
    const unsigned short* __restrict__ qg, const unsigned short* __restrict__ kgl,
    const unsigned short* __restrict__ vg, const float* __restrict__ rpt,
    unsigned short* __restrict__ out) {
    __shared__ __align__(16) unsigned short sm[4][6144];
    __shared__ unsigned short rpts[169 * 8];
    const int tid = threadIdx.x, wid = tid >> 6, lane = tid & 63;
    for (int i = tid; i < 169 * 8; i += 256) rpts[i] = f2b(rpt[i]);
    const int task = blockIdx.x * 4 + wid;
    const int w = task >> 3, h = task & 7;
    const int widx = w & 63, wy = widx >> 3, wx = widx & 7;
    unsigned short* q_s = sm[wid];
    unsigned short* k_s = sm[wid] + 2048;
    unsigned short* v_s = sm[wid] + 4096;
    unsigned short* p_s = sm[wid];
    const unsigned short* qsrc = qg + (size_t)task * 1568;
    const unsigned short* ksrc = kgl + (size_t)task * 1568;
    const unsigned short* vsrc = vg + (size_t)task * 2048;
    for (int c = lane; c < 196; c += 64) {
        int row = c >> 2, kc = c & 3;
        int off = (row * 32 + kc * 8) ^ ((row & 7) << 3);
        *reinterpret_cast<short8*>(q_s + off) =
            *reinterpret_cast<const short8*>(qsrc + c * 8);
        *reinterpret_cast<short8*>(k_s + off) =
            *reinterpret_cast<const short8*>(ksrc + c * 8);
    }
#pragma unroll
    for (int i = 0; i < 4; i++) {
        int c = i * 64 + lane;
        int row = c >> 3, kc = c & 7;
        int off = (row * 64 + kc * 8) ^ ((row & 7) << 3);
        *reinterpret_cast<short8*>(v_s + off) =
            *reinterpret_cast<const short8*>(vsrc + c * 8);
    }
    __syncthreads();

    const int lr = lane & 15, kg = lane >> 4;
    short8 af[4], bf[4];
#pragma unroll
    for (int mf = 0; mf < 4; mf++) {
        int r = mf * 16 + lr;
        af[mf] = *reinterpret_cast<const short8*>(
            q_s + ((r * 32 + kg * 8) ^ ((r & 7) << 3)));
    }
#pragma unroll
    for (int nf = 0; nf < 4; nf++) {
        int r = nf * 16 + lr;
        bf[nf] = *reinterpret_cast<const short8*>(
            k_s + ((r * 32 + kg * 8) ^ ((r & 7) << 3)));
    }
    f32x4 s[4][4] = {};
#pragma unroll
    for (int mf = 0; mf < 4; mf++)
#pragma unroll
        for (int nf = 0; nf < 4; nf++)
            s[mf][nf] = __builtin_amdgcn_mfma_f32_16x16x32_bf16(af[mf], bf[nf],
                                                                s[mf][nf], 0, 0, 0);
#pragma unroll
    for (int mf = 0; mf < 4; mf++) {
#pragma unroll
        for (int j = 0; j < 4; j++) {
            int row = mf * 16 + kg * 4 + j;
            bool rvalid = row < 49;
            int qy = 0, qx = 0, gq = 0;
            if (rvalid) {
                qy = row / 7; qx = row - qy * 7;
                int yi = wy * 7 + qy, xi = wx * 7 + qx;
                gq = ((yi < 49) ? 0 : ((yi < 53) ? 1 : 2)) * 3 +
                     ((xi < 49) ? 0 : ((xi < 53) ? 1 : 2));
            }
            float L[4];
#pragma unroll
            for (int nf = 0; nf < 4; nf++) {
                int col = nf * 16 + lr;
                float val = s[mf][nf][j];
                if (rvalid && col < 49) {
                    int ky = col / 7, kx = col - ky * 7;
                    int yi = wy * 7 + ky, xi = wx * 7 + kx;
                    int gk = ((yi < 49) ? 0 : ((yi < 53) ? 1 : 2)) * 3 +
                             ((xi < 49) ? 0 : ((xi < 53) ? 1 : 2));
                    val += b2f(rpts[((qy - ky + 6) * 13 + (qx - kx + 6)) * 8 + h]);
                    if (gq != gk) val -= 100.0f;
                } else {
                    val = -1e30f;
                }
                L[nf] = val;
            }
            float m = fmaxf(fmaxf(L[0], L[1]), fmaxf(L[2], L[3]));
#pragma unroll
            for (int t2 = 1; t2 < 16; t2 <<= 1) m = fmaxf(m, __shfl_xor(m, t2));
            float P[4], psum = 0.f;
#pragma unroll
            for (int nf = 0; nf < 4; nf++) {
                P[nf] = __expf(L[nf] - m);
                psum += P[nf];
            }
#pragma unroll
            for (int t2 = 1; t2 < 16; t2 <<= 1) psum += __shfl_xor(psum, t2);
            float inv = 1.0f / psum;
#pragma unroll
            for (int nf = 0; nf < 4; nf++) {
                int col = nf * 16 + lr;
                p_s[(row * 64 + col) ^ ((row & 7) << 3)] = f2b(P[nf] * inv);
            }
        }
    }
    f32x4 o[4][2] = {};
#pragma unroll
    for (int ks = 0; ks < 2; ks++) {
        short8 pa[4], vb[2];
#pragma unroll
        for (int mf = 0; mf < 4; mf++) {
            int r = mf * 16 + lr;
            pa[mf] = *reinterpret_cast<const short8*>(
                p_s + ((r * 64 + ks * 32 + kg * 8) ^ ((r & 7) << 3)));
        }
#pragma unroll
        for (int nf = 0; nf < 2; nf++) {
            int d = nf * 16 + lr;
            vb[nf] = *reinterpret_cast<const short8*>(
                v_s + ((d * 64 + ks * 32 + kg * 8) ^ ((d & 7) << 3)));
        }
#pragma unroll
        for (int mf = 0; mf < 4; mf++)
#pragma unroll
            for (int nf = 0; nf < 2; nf++)
                o[mf][nf] = __builtin_amdgcn_mfma_f32_16x16x32_bf16(
                    pa[mf], vb[nf], o[mf][nf], 0, 0, 0);
    }
#pragma unroll
    for (int mf = 0; mf < 4; mf++) {
#pragma unroll
        for (int j = 0; j < 4; j++) {
            int row = mf * 16 + kg * 4 + j;
            if (row < 49) {
#pragma unroll
                for (int nf = 0; nf < 2; nf++) {
                    int d = nf * 16 + lr;
                    out[((size_t)w * 49 + row) * 256 + h * 32 + d] =
                        f2b(o[mf][nf][j]);
                }
            }
        }
    }
}

// ---------------- launcher --------------------------------------------------
extern "C" void kernel_launch(void* const* d_in, const int* in_sizes, int n_in,
                              void* d_out, int out_size, void* d_ws,
                              size_t ws_size, hipStream_t stream) {
    const float* x     = (const float*)d_in[0];
    const float* g1    = (const float*)d_in[1];
    const float* be1   = (const float*)d_in[2];
    const float* wqkv  = (const float*)d_in[3];
    const float* bqkv  = (const float*)d_in[4];
    const float* rpt   = (const float*)d_in[5];
    const float* wproj = (const float*)d_in[6];
    const float* bproj = (const float*)d_in[7];
    const float* g2    = (const float*)d_in[8];
    const float* be2   = (const float*)d_in[9];
    const float* wfc1  = (const float*)d_in[10];
    const float* bfc1  = (const float*)d_in[11];
    const float* wfc2  = (const float*)d_in[12];
    const float* bfc2  = (const float*)d_in[13];
    float* out = (float*)d_out;
    char* ws = (char*)d_ws;

    unsigned short* hb  = (unsigned short*)(ws);              // 25,690,112 B
    unsigned short* qg  = (unsigned short*)(ws + 25690112);   // 25,690,112
    unsigned short* kgl = (unsigned short*)(ws + 51380224);   // 25,690,112
    unsigned short* vg  = (unsigned short*)(ws + 77070336);   // 33,554,432
    unsigned short* x2b = (unsigned short*)(ws + 110624768);  // 25,690,112 (bf16)
    unsigned short* h2  = (unsigned short*)(ws + 162004992);  // 25,690,112
    unsigned short* wT  = (unsigned short*)(ws + 187695104);  // 1,572,864
    unsigned short* wqkvT = wT;
    unsigned short* wprojT = wT + 196608;
    unsigned short* wfc1T  = wT + 262144;
    unsigned short* wfc2T  = wT + 524288;
    unsigned short* a1 = (unsigned short*)ws;  // aliases dead hb/q/k/v

    wconv_kernel<<<(256 * 768 + 255) / 256, 256, 0, stream>>>(wqkv, wqkvT, 256, 768);
    wconv_kernel<<<(256 * 256 + 255) / 256, 256, 0, stream>>>(wproj, wprojT, 256, 256);
    wconv_kernel<<<(256 * 1024 + 255) / 256, 256, 0, stream>>>(wfc1, wfc1T, 256, 1024);
    wconv_kernel<<<(1024 * 256 + 255) / 256, 256, 0, stream>>>(wfc2, wfc2T, 1024, 256);
    // no v-pad memset: pad cols (p>=49) multiply by exactly-zero P; 0xAA bf16
    // poison and stale bf16 values are always finite.

    ln_kernel<1, float><<<12544, 256, 0, stream>>>(x, g1, be1, hb);
    gemm_k256_kernel<0><<<dim3(6, 98), 256, 0, stream>>>(
        hb, wqkvT, bqkv, nullptr, nullptr, qg, kgl, vg);
    attn_kernel<<<2048, 256, 0, stream>>>(qg, kgl, vg, rpt, hb);
    gemm_k256_kernel<1><<<dim3(2, 98), 256, 0, stream>>>(
        hb, wprojT, bproj, x2b, x, nullptr, nullptr, nullptr);
    ln_kernel<0, unsigned short><<<12544, 256, 0, stream>>>(x2b, g2, be2, h2);
    gemm_k256_kernel<2><<<dim3(8, 98), 256, 0, stream>>>(
        h2, wfc1T, bfc1, a1, nullptr, nullptr, nullptr, nullptr);
    gemm_kernel<1024, 3><<<dim3(2, 392), 256, 0, stream>>>(
        a1, wfc2T, bfc2, out, x2b, nullptr, nullptr, nullptr);
}

// Round 12
// 295.847 us; speedup vs baseline: 1.4753x; 1.0890x over previous
//
#include <hip/hip_runtime.h>
#include <hip/hip_bf16.h>
#include <cstdint>
#include <cstddef>
#include <type_traits>

typedef __attribute__((ext_vector_type(8))) short short8;
typedef __attribute__((ext_vector_type(4))) float f32x4;
typedef __attribute__((ext_vector_type(4))) unsigned short us4;

#define DEVINL __device__ __forceinline__

static constexpr int SS_ = 3;
static constexpr int HH = 56, WW = 56;
#define SCALE_Q 0.17677669529663689f   // 32^-0.5

DEVINL unsigned short f2b(float f) {
    unsigned int u = __builtin_bit_cast(unsigned int, f);
    unsigned int r = (u + 0x7FFFu + ((u >> 16) & 1u)) >> 16;
    return (unsigned short)r;
}
DEVINL float b2f(unsigned short s) {
    return __builtin_bit_cast(float, ((unsigned int)s) << 16);
}

// fast GELU: v * sigmoid(1.702 v)  (~6 VALU vs 13 for erf-poly; |eps|<=0.009,
// attenuated to ~0.005 at the block output through FC2's 0.02-scale weights)
DEVINL float gelu(float v) {
    float e = __expf(-1.702f * v);
    return v * __builtin_amdgcn_rcpf(1.0f + e);
}

// async global->LDS, 16B per lane. LDS dest must be wave-uniform base + lane*16.
DEVINL void gload_lds16(const unsigned short* g, unsigned short* l) {
    __builtin_amdgcn_global_load_lds(
        (const __attribute__((address_space(1))) unsigned int*)g,
        (__attribute__((address_space(3))) unsigned int*)l, 16, 0, 0);
}

// ---------------- weight convert + transpose: out[n][k] = bf16(in[k][n]) ----
__global__ void wconv_kernel(const float* __restrict__ in,
                             unsigned short* __restrict__ out, int K, int N) {
    int i = blockIdx.x * 256 + threadIdx.x;
    if (i >= K * N) return;
    int k = i / N, n = i - k * N;
    out[(size_t)n * K + k] = f2b(in[i]);
}

// ---------------- LayerNorm (one wave per token), optional window gather ----
template <int MODE, typename TIN>
__global__ __launch_bounds__(256) void ln_kernel(
    const TIN* __restrict__ x, const float* __restrict__ g,
    const float* __restrict__ be, unsigned short* __restrict__ out) {
    const int wid = threadIdx.x >> 6, lane = threadIdx.x & 63;
    const int t = blockIdx.x * 4 + wid;
    int src;
    if constexpr (MODE == 1) {
        int w = t / 49, p = t - w * 49;
        int b = w >> 6, widx = w & 63;
        int wy = widx >> 3, wx = widx & 7;
        int py = p / 7, px = p - py * 7;
        int y = wy * 7 + py + SS_;  if (y >= HH) y -= HH;
        int xx = wx * 7 + px + SS_; if (xx >= WW) xx -= WW;
        src = b * (HH * WW) + y * WW + xx;
    } else {
        src = t;
    }
    float4 v;
    if constexpr (std::is_same_v<TIN, float>) {
        v = reinterpret_cast<const float4*>(x + (size_t)src * 256)[lane];
    } else {
        us4 u = reinterpret_cast<const us4*>(x + (size_t)src * 256)[lane];
        v.x = b2f(u.x); v.y = b2f(u.y); v.z = b2f(u.z); v.w = b2f(u.w);
    }
    float s = v.x + v.y + v.z + v.w;
    float q = v.x * v.x + v.y * v.y + v.z * v.z + v.w * v.w;
#pragma unroll
    for (int m = 1; m < 64; m <<= 1) {
        s += __shfl_xor(s, m);
        q += __shfl_xor(q, m);
    }
    float mean = s * (1.0f / 256.0f);
    float var = q * (1.0f / 256.0f) - mean * mean;
    float rs = rsqrtf(var + 1e-5f);
    int c = lane * 4;
    us4 o;
    o.x = f2b((v.x - mean) * rs * g[c + 0] + be[c + 0]);
    o.y = f2b((v.y - mean) * rs * g[c + 1] + be[c + 1]);
    o.z = f2b((v.z - mean) * rs * g[c + 2] + be[c + 2]);
    o.w = f2b((v.w - mean) * rs * g[c + 3] + be[c + 3]);
    *reinterpret_cast<us4*>(out + (size_t)t * 256 + c) = o;
}

// ---------------- GEMM: C[M,N] = A[M,K] @ Bt[N,K]^T + bias, epilogues -------
// R7 body (proven 288us total): 128x128 tile, BK=64, 4 waves (2x2), 256
// threads, single-buffered 32KB LDS. __launch_bounds__(256,4).
// Bijective XCD-chunk swizzle (proven FETCH 73->18MB); pre-swizzled global
// source for global_load_lds; ds_read_b128 with matching XOR swizzle.
// EPI 0: qkv scatter.  EPI 1: proj + window-reverse + residual(fp32) -> bf16.
// EPI 2: fast-GELU -> bf16.  EPI 3: + residual(bf16) -> fp32 out.
template <int KDIM, int EPI>
__global__ __launch_bounds__(256, 4) void gemm_kernel(
    const unsigned short* __restrict__ A, const unsigned short* __restrict__ Bt,
    const float* __restrict__ bias, void* __restrict__ out0,
    const void* __restrict__ res, unsigned short* __restrict__ o_q,
    unsigned short* __restrict__ o_k, unsigned short* __restrict__ o_v) {
    constexpr int BM = 128, BN = 128, BK = 64;
    __shared__ __align__(16) unsigned short As[BM * BK];
    __shared__ __align__(16) unsigned short Bs[BN * BK];
    const int tid = threadIdx.x;
    const int wid = tid >> 6, lane = tid & 63;

    // XCD-chunk swizzle (bijective: total blocks divisible by 8)
    const int nwg = gridDim.x * gridDim.y;
    const int bid = blockIdx.x + gridDim.x * blockIdx.y;
    const int nb = (bid & 7) * (nwg >> 3) + (bid >> 3);
    const int n0 = (nb % gridDim.x) * BN;
    const int m0 = (nb / gridDim.x) * BM;

    const int wm = wid >> 1, wn = wid & 1;
    const int lr = lane & 15, kg = lane >> 4;
    f32x4 acc[4][4] = {};

    // staging geometry: round i, thread tid handles flat chunk f = i*256+tid
    // row = f>>3, stored chunk pos = tid&7; global chunk = pos ^ (row&7)
    const int srow = tid >> 3;
    const int spos = tid & 7;

    for (int kt = 0; kt < KDIM; kt += BK) {
#pragma unroll
        for (int i = 0; i < 4; i++) {
            int row = i * 32 + srow;
            gload_lds16(A + (size_t)(m0 + row) * KDIM + kt + ((spos ^ (row & 7)) << 3),
                        As + i * 2048 + tid * 8);
        }
#pragma unroll
        for (int i = 0; i < 4; i++) {
            int row = i * 32 + srow;
            gload_lds16(Bt + (size_t)(n0 + row) * KDIM + kt + ((spos ^ (row & 7)) << 3),
                        Bs + i * 2048 + tid * 8);
        }
        __syncthreads();
#pragma unroll
        for (int ks = 0; ks < 2; ks++) {
            short8 a[4], b[4];
#pragma unroll
            for (int mf = 0; mf < 4; mf++) {
                int r = wm * 64 + mf * 16 + lr;
                a[mf] = *reinterpret_cast<const short8*>(
                    As + r * 64 + (((ks * 4 + kg) ^ (r & 7)) << 3));
            }
#pragma unroll
            for (int nf = 0; nf < 4; nf++) {
                int r = wn * 64 + nf * 16 + lr;
                b[nf] = *reinterpret_cast<const short8*>(
                    Bs + r * 64 + (((ks * 4 + kg) ^ (r & 7)) << 3));
            }
#pragma unroll
            for (int mf = 0; mf < 4; mf++)
#pragma unroll
                for (int nf = 0; nf < 4; nf++)
                    acc[mf][nf] = __builtin_amdgcn_mfma_f32_16x16x32_bf16(
                        a[mf], b[nf], acc[mf][nf], 0, 0, 0);
        }
        __syncthreads();
    }

#pragma unroll
    for (int mf = 0; mf < 4; mf++) {
#pragma unroll
        for (int nf = 0; nf < 4; nf++) {
#pragma unroll
            for (int j = 0; j < 4; j++) {
                int row = m0 + wm * 64 + mf * 16 + kg * 4 + j;
                int col = n0 + wn * 64 + nf * 16 + lr;
                float v = acc[mf][nf][j] + bias[col];
                if constexpr (EPI == 0) {
                    int w = row / 49, p = row - w * 49;
                    int which = col >> 8, h = (col >> 5) & 7, d = col & 31;
                    size_t th = (size_t)(w * 8 + h);
                    if (which == 0)
                        o_q[th * 1568 + p * 32 + d] = f2b(v * SCALE_Q);
                    else if (which == 1)
                        o_k[th * 1568 + p * 32 + d] = f2b(v);
                    else
                        o_v[th * 2048 + d * 64 + p] = f2b(v);
                } else if constexpr (EPI == 1) {
                    int w = row / 49, p = row - w * 49;
                    int b2 = w >> 6, widx = w & 63;
                    int wy = widx >> 3, wx = widx & 7;
                    int py = p / 7, px = p - py * 7;
                    int y = wy * 7 + py + SS_;  if (y >= HH) y -= HH;
                    int xx = wx * 7 + px + SS_; if (xx >= WW) xx -= WW;
                    size_t oi = ((size_t)(b2 * 3136 + y * 56 + xx)) * 256 + col;
                    reinterpret_cast<unsigned short*>(out0)[oi] =
                        f2b(v + reinterpret_cast<const float*>(res)[oi]);
                } else if constexpr (EPI == 2) {
                    reinterpret_cast<unsigned short*>(out0)[(size_t)row * 1024 + col] =
                        f2b(gelu(v));
                } else {
                    size_t oi = (size_t)row * 256 + col;
                    reinterpret_cast<float*>(out0)[oi] =
                        v + b2f(reinterpret_cast<const unsigned short*>(res)[oi]);
                }
            }
        }
    }
}

// ---------------- fused window attention: one wave per (window, head) -------
__global__ __launch_bounds__(256) void attn_kernel(
    const unsigned short* __restrict__ qg, const unsigned short* __restrict__ kgl,
    const unsigned short* __restrict__ vg, const float* __restrict__ rpt,
    unsigned short* __restrict__ out) {
    __shared__ __align__(16) unsigned short sm[4][6144];
    __shared__ unsigned short rpts[169 * 8];
    const int tid = threadIdx.x, wid = tid >> 6, lane = tid & 63;
    for (int i = tid; i < 169 * 8; i += 256) rpts[i] = f2b(rpt[i]);
    const int task = blockIdx.x * 4 + wid;
    const int w = task >> 3, h = task & 7;
    const int widx = w & 63, wy = widx >> 3, wx = widx & 7;
    unsigned short* q_s = sm[wid];
    unsigned short* k_s = sm[wid] + 2048;
    unsigned short* v_s = sm[wid] + 4096;
    unsigned short* p_s = sm[wid];
    const unsigned short* qsrc = qg + (size_t)task * 1568;
    const unsigned short* ksrc = kgl + (size_t)task * 1568;
    const unsigned short* vsrc = vg + (size_t)task * 2048;
    for (int c = lane; c < 196; c += 64) {
        int row = c >> 2, kc = c & 3;
        int off = (row * 32 + kc * 8) ^ ((row & 7) << 3);
        *reinterpret_cast<short8*>(q_s + off) =
            *reinterpret_cast<const short8*>(qsrc + c * 8);
        *reinterpret_cast<short8*>(k_s + off) =
            *reinterpret_cast<const short8*>(ksrc + c * 8);
    }
#pragma unroll
    for (int i = 0; i < 4; i++) {
        int c = i * 64 + lane;
        int row = c >> 3, kc = c & 7;
        int off = (row * 64 + kc * 8) ^ ((row & 7) << 3);
        *reinterpret_cast<short8*>(v_s + off) =
            *reinterpret_cast<const short8*>(vsrc + c * 8);
    }
    __syncthreads();

    const int lr = lane & 15, kg = lane >> 4;
    short8 af[4], bf[4];
#pragma unroll
    for (int mf = 0; mf < 4; mf++) {
        int r = mf * 16 + lr;
        af[mf] = *reinterpret_cast<const short8*>(
            q_s + ((r * 32 + kg * 8) ^ ((r & 7) << 3)));
    }
#pragma unroll
    for (int nf = 0; nf < 4; nf++) {
        int r = nf * 16 + lr;
        bf[nf] = *reinterpret_cast<const short8*>(
            k_s + ((r * 32 + kg * 8) ^ ((r & 7) << 3)));
    }
    f32x4 s[4][4] = {};
#pragma unroll
    for (int mf = 0; mf < 4; mf++)
#pragma unroll
        for (int nf = 0; nf < 4; nf++)
            s[mf][nf] = __builtin_amdgcn_mfma_f32_16x16x32_bf16(af[mf], bf[nf],
                                                                s[mf][nf], 0, 0, 0);
#pragma unroll
    for (int mf = 0; mf < 4; mf++) {
#pragma unroll
        for (int j = 0; j < 4; j++) {
            int row = mf * 16 + kg * 4 + j;
            bool rvalid = row < 49;
            int qy = 0, qx = 0, gq = 0;
            if (rvalid) {
                qy = row / 7; qx = row - qy * 7;
                int yi = wy * 7 + qy, xi = wx * 7 + qx;
                gq = ((yi < 49) ? 0 : ((yi < 53) ? 1 : 2)) * 3 +
                     ((xi < 49) ? 0 : ((xi < 53) ? 1 : 2));
            }
            float L[4];
#pragma unroll
            for (int nf = 0; nf < 4; nf++) {
                int col = nf * 16 + lr;
                float val = s[mf][nf][j];
                if (rvalid && col < 49) {
                    int ky = col / 7, kx = col - ky * 7;
                    int yi = wy * 7 + ky, xi = wx * 7 + kx;
                    int gk = ((yi < 49) ? 0 : ((yi < 53) ? 1 : 2)) * 3 +
                             ((xi < 49) ? 0 : ((xi < 53) ? 1 : 2));
                    val += b2f(rpts[((qy - ky + 6) * 13 + (qx - kx + 6)) * 8 + h]);
                    if (gq != gk) val -= 100.0f;
                } else {
                    val = -1e30f;
                }
                L[nf] = val;
            }
            float m = fmaxf(fmaxf(L[0], L[1]), fmaxf(L[2], L[3]));
#pragma unroll
            for (int t2 = 1; t2 < 16; t2 <<= 1) m = fmaxf(m, __shfl_xor(m, t2));
            float P[4], psum = 0.f;
#pragma unroll
            for (int nf = 0; nf < 4; nf++) {
                P[nf] = __expf(L[nf] - m);
                psum += P[nf];
            }
#pragma unroll
            for (int t2 = 1; t2 < 16; t2 <<= 1) psum += __shfl_xor(psum, t2);
            float inv = 1.0f / psum;
#pragma unroll
            for (int nf = 0; nf < 4; nf++) {
                int col = nf * 16 + lr;
                p_s[(row * 64 + col) ^ ((row & 7) << 3)] = f2b(P[nf] * inv);
            }
        }
    }
    f32x4 o[4][2] = {};
#pragma unroll
    for (int ks = 0; ks < 2; ks++) {
        short8 pa[4], vb[2];
#pragma unroll
        for (int mf = 0; mf < 4; mf++) {
            int r = mf * 16 + lr;
            pa[mf] = *reinterpret_cast<const short8*>(
                p_s + ((r * 64 + ks * 32 + kg * 8) ^ ((r & 7) << 3)));
        }
#pragma unroll
        for (int nf = 0; nf < 2; nf++) {
            int d = nf * 16 + lr;
            vb[nf] = *reinterpret_cast<const short8*>(
                v_s + ((d * 64 + ks * 32 + kg * 8) ^ ((d & 7) << 3)));
        }
#pragma unroll
        for (int mf = 0; mf < 4; mf++)
#pragma unroll
            for (int nf = 0; nf < 2; nf++)
                o[mf][nf] = __builtin_amdgcn_mfma_f32_16x16x32_bf16(
                    pa[mf], vb[nf], o[mf][nf], 0, 0, 0);
    }
#pragma unroll
    for (int mf = 0; mf < 4; mf++) {
#pragma unroll
        for (int j = 0; j < 4; j++) {
            int row = mf * 16 + kg * 4 + j;
            if (row < 49) {
#pragma unroll
                for (int nf = 0; nf < 2; nf++) {
                    int d = nf * 16 + lr;
                    out[((size_t)w * 49 + row) * 256 + h * 32 + d] =
                        f2b(o[mf][nf][j]);
                }
            }
        }
    }
}

// ---------------- launcher --------------------------------------------------
extern "C" void kernel_launch(void* const* d_in, const int* in_sizes, int n_in,
                              void* d_out, int out_size, void* d_ws,
                              size_t ws_size, hipStream_t stream) {
    const float* x     = (const float*)d_in[0];
    const float* g1    = (const float*)d_in[1];
    const float* be1   = (const float*)d_in[2];
    const float* wqkv  = (const float*)d_in[3];
    const float* bqkv  = (const float*)d_in[4];
    const float* rpt   = (const float*)d_in[5];
    const float* wproj = (const float*)d_in[6];
    const float* bproj = (const float*)d_in[7];
    const float* g2    = (const float*)d_in[8];
    const float* be2   = (const float*)d_in[9];
    const float* wfc1  = (const float*)d_in[10];
    const float* bfc1  = (const float*)d_in[11];
    const float* wfc2  = (const float*)d_in[12];
    const float* bfc2  = (const float*)d_in[13];
    float* out = (float*)d_out;
    char* ws = (char*)d_ws;

    unsigned short* hb  = (unsigned short*)(ws);              // 25,690,112 B
    unsigned short* qg  = (unsigned short*)(ws + 25690112);   // 25,690,112
    unsigned short* kgl = (unsigned short*)(ws + 51380224);   // 25,690,112
    unsigned short* vg  = (unsigned short*)(ws + 77070336);   // 33,554,432
    unsigned short* x2b = (unsigned short*)(ws + 110624768);  // 25,690,112 (bf16)
    unsigned short* h2  = (unsigned short*)(ws + 162004992);  // 25,690,112
    unsigned short* wT  = (unsigned short*)(ws + 187695104);  // 1,572,864
    unsigned short* wqkvT = wT;
    unsigned short* wprojT = wT + 196608;
    unsigned short* wfc1T  = wT + 262144;
    unsigned short* wfc2T  = wT + 524288;
    unsigned short* a1 = (unsigned short*)ws;  // aliases dead hb/q/k/v

    wconv_kernel<<<(256 * 768 + 255) / 256, 256, 0, stream>>>(wqkv, wqkvT, 256, 768);
    wconv_kernel<<<(256 * 256 + 255) / 256, 256, 0, stream>>>(wproj, wprojT, 256, 256);
    wconv_kernel<<<(256 * 1024 + 255) / 256, 256, 0, stream>>>(wfc1, wfc1T, 256, 1024);
    wconv_kernel<<<(1024 * 256 + 255) / 256, 256, 0, stream>>>(wfc2, wfc2T, 1024, 256);
    // no v-pad memset: pad cols (p>=49) multiply by exactly-zero P; 0xAA bf16
    // poison and stale bf16 values are always finite.

    ln_kernel<1, float><<<12544, 256, 0, stream>>>(x, g1, be1, hb);
    gemm_kernel<256, 0><<<dim3(6, 392), 256, 0, stream>>>(
        hb, wqkvT, bqkv, nullptr, nullptr, qg, kgl, vg);
    attn_kernel<<<2048, 256, 0, stream>>>(qg, kgl, vg, rpt, hb);
    gemm_kernel<256, 1><<<dim3(2, 392), 256, 0, stream>>>(
        hb, wprojT, bproj, x2b, x, nullptr, nullptr, nullptr);
    ln_kernel<0, unsigned short><<<12544, 256, 0, stream>>>(x2b, g2, be2, h2);
    gemm_kernel<256, 2><<<dim3(8, 392), 256, 0, stream>>>(
        h2, wfc1T, bfc1, a1, nullptr, nullptr, nullptr, nullptr);
    gemm_kernel<1024, 3><<<dim3(2, 392), 256, 0, stream>>>(
        a1, wfc2T, bfc2, out, x2b, nullptr, nullptr, nullptr);
}

// Round 13
// 264.186 us; speedup vs baseline: 1.6521x; 1.1198x over previous
//
#include <hip/hip_runtime.h>
#include <hip/hip_bf16.h>
#include <cstdint>
#include <cstddef>
#include <type_traits>

typedef __attribute__((ext_vector_type(8))) short short8;
typedef __attribute__((ext_vector_type(4))) float f32x4;
typedef __attribute__((ext_vector_type(4))) unsigned short us4;

#define DEVINL __device__ __forceinline__

static constexpr int SS_ = 3;
static constexpr int HH = 56, WW = 56;
#define SCALE_Q 0.17677669529663689f   // 32^-0.5

DEVINL unsigned short f2b(float f) {
    unsigned int u = __builtin_bit_cast(unsigned int, f);
    unsigned int r = (u + 0x7FFFu + ((u >> 16) & 1u)) >> 16;
    return (unsigned short)r;
}
DEVINL float b2f(unsigned short s) {
    return __builtin_bit_cast(float, ((unsigned int)s) << 16);
}

// GELU with 3-term A&S 7.1.25 erf (|eps|<=2.5e-5 -> gelu abs err ~1e-4)
DEVINL float gelu(float v) {
    float ax = fabsf(v) * 0.70710678118654752f;
    float t = 1.0f / (1.0f + 0.47047f * ax);
    float poly = t * (0.3480242f + t * (-0.0958798f + t * 0.7478556f));
    float erfv = 1.0f - poly * __expf(-ax * ax);
    erfv = v >= 0.0f ? erfv : -erfv;
    return 0.5f * v * (1.0f + erfv);
}

// async global->LDS, 16B per lane. LDS dest must be wave-uniform base + lane*16.
DEVINL void gload_lds16(const unsigned short* g, unsigned short* l) {
    __builtin_amdgcn_global_load_lds(
        (const __attribute__((address_space(1))) unsigned int*)g,
        (__attribute__((address_space(3))) unsigned int*)l, 16, 0, 0);
}

// ---------------- weight convert + transpose: out[n][k] = bf16(in[k][n]) ----
__global__ void wconv_kernel(const float* __restrict__ in,
                             unsigned short* __restrict__ out, int K, int N) {
    int i = blockIdx.x * 256 + threadIdx.x;
    if (i >= K * N) return;
    int k = i / N, n = i - k * N;
    out[(size_t)n * K + k] = f2b(in[i]);
}

// ---------------- LayerNorm (one wave per token), optional window gather ----
template <int MODE, typename TIN>
__global__ __launch_bounds__(256) void ln_kernel(
    const TIN* __restrict__ x, const float* __restrict__ g,
    const float* __restrict__ be, unsigned short* __restrict__ out) {
    const int wid = threadIdx.x >> 6, lane = threadIdx.x & 63;
    const int t = blockIdx.x * 4 + wid;
    int src;
    if constexpr (MODE == 1) {
        int w = t / 49, p = t - w * 49;
        int b = w >> 6, widx = w & 63;
        int wy = widx >> 3, wx = widx & 7;
        int py = p / 7, px = p - py * 7;
        int y = wy * 7 + py + SS_;  if (y >= HH) y -= HH;
        int xx = wx * 7 + px + SS_; if (xx >= WW) xx -= WW;
        src = b * (HH * WW) + y * WW + xx;
    } else {
        src = t;
    }
    float4 v;
    if constexpr (std::is_same_v<TIN, float>) {
        v = reinterpret_cast<const float4*>(x + (size_t)src * 256)[lane];
    } else {
        us4 u = reinterpret_cast<const us4*>(x + (size_t)src * 256)[lane];
        v.x = b2f(u.x); v.y = b2f(u.y); v.z = b2f(u.z); v.w = b2f(u.w);
    }
    float s = v.x + v.y + v.z + v.w;
    float q = v.x * v.x + v.y * v.y + v.z * v.z + v.w * v.w;
#pragma unroll
    for (int m = 1; m < 64; m <<= 1) {
        s += __shfl_xor(s, m);
        q += __shfl_xor(q, m);
    }
    float mean = s * (1.0f / 256.0f);
    float var = q * (1.0f / 256.0f) - mean * mean;
    float rs = rsqrtf(var + 1e-5f);
    int c = lane * 4;
    us4 o;
    o.x = f2b((v.x - mean) * rs * g[c + 0] + be[c + 0]);
    o.y = f2b((v.y - mean) * rs * g[c + 1] + be[c + 1]);
    o.z = f2b((v.z - mean) * rs * g[c + 2] + be[c + 2]);
    o.w = f2b((v.w - mean) * rs * g[c + 3] + be[c + 3]);
    *reinterpret_cast<us4*>(out + (size_t)t * 256 + c) = o;
}

// ---------------- GEMM: C[M,N] = A[M,K] @ Bt[N,K]^T + bias, epilogues -------
// R7 body (proven): 128x128 tile, BK=64, 4 waves (2x2), 256 threads,
// single-buffered 32KB LDS. __launch_bounds__(256,4).
// Bijective XCD-chunk swizzle (proven FETCH 73->18MB); pre-swizzled global
// source for global_load_lds; ds_read_b128 with matching XOR swizzle.
// EPI 0: qkv scatter -- v now P-MAJOR like k (R12 profile: the d-major v
//        scatter caused 2x write amplification, QKV WRITE 179MB vs 85 ideal;
//        attention re-transposes during its LDS staging instead).
// EPI 1: proj + window-reverse + residual(fp32) -> bf16.
// EPI 2: GELU -> bf16.  EPI 3: + residual(bf16) -> fp32 out.
template <int KDIM, int EPI>
__global__ __launch_bounds__(256, 4) void gemm_kernel(
    const unsigned short* __restrict__ A, const unsigned short* __restrict__ Bt,
    const float* __restrict__ bias, void* __restrict__ out0,
    const void* __restrict__ res, unsigned short* __restrict__ o_q,
    unsigned short* __restrict__ o_k, unsigned short* __restrict__ o_v) {
    constexpr int BM = 128, BN = 128, BK = 64;
    __shared__ __align__(16) unsigned short As[BM * BK];
    __shared__ __align__(16) unsigned short Bs[BN * BK];
    const int tid = threadIdx.x;
    const int wid = tid >> 6, lane = tid & 63;

    // XCD-chunk swizzle (bijective: total blocks divisible by 8)
    const int nwg = gridDim.x * gridDim.y;
    const int bid = blockIdx.x + gridDim.x * blockIdx.y;
    const int nb = (bid & 7) * (nwg >> 3) + (bid >> 3);
    const int n0 = (nb % gridDim.x) * BN;
    const int m0 = (nb / gridDim.x) * BM;

    const int wm = wid >> 1, wn = wid & 1;
    const int lr = lane & 15, kg = lane >> 4;
    f32x4 acc[4][4] = {};

    // staging geometry: round i, thread tid handles flat chunk f = i*256+tid
    // row = f>>3, stored chunk pos = tid&7; global chunk = pos ^ (row&7)
    const int srow = tid >> 3;
    const int spos = tid & 7;

    for (int kt = 0; kt < KDIM; kt += BK) {
#pragma unroll
        for (int i = 0; i < 4; i++) {
            int row = i * 32 + srow;
            gload_lds16(A + (size_t)(m0 + row) * KDIM + kt + ((spos ^ (row & 7)) << 3),
                        As + i * 2048 + tid * 8);
        }
#pragma unroll
        for (int i = 0; i < 4; i++) {
            int row = i * 32 + srow;
            gload_lds16(Bt + (size_t)(n0 + row) * KDIM + kt + ((spos ^ (row & 7)) << 3),
                        Bs + i * 2048 + tid * 8);
        }
        __syncthreads();
#pragma unroll
        for (int ks = 0; ks < 2; ks++) {
            short8 a[4], b[4];
#pragma unroll
            for (int mf = 0; mf < 4; mf++) {
                int r = wm * 64 + mf * 16 + lr;
                a[mf] = *reinterpret_cast<const short8*>(
                    As + r * 64 + (((ks * 4 + kg) ^ (r & 7)) << 3));
            }
#pragma unroll
            for (int nf = 0; nf < 4; nf++) {
                int r = wn * 64 + nf * 16 + lr;
                b[nf] = *reinterpret_cast<const short8*>(
                    Bs + r * 64 + (((ks * 4 + kg) ^ (r & 7)) << 3));
            }
#pragma unroll
            for (int mf = 0; mf < 4; mf++)
#pragma unroll
                for (int nf = 0; nf < 4; nf++)
                    acc[mf][nf] = __builtin_amdgcn_mfma_f32_16x16x32_bf16(
                        a[mf], b[nf], acc[mf][nf], 0, 0, 0);
        }
        __syncthreads();
    }

#pragma unroll
    for (int mf = 0; mf < 4; mf++) {
#pragma unroll
        for (int nf = 0; nf < 4; nf++) {
#pragma unroll
            for (int j = 0; j < 4; j++) {
                int row = m0 + wm * 64 + mf * 16 + kg * 4 + j;
                int col = n0 + wn * 64 + nf * 16 + lr;
                float v = acc[mf][nf][j] + bias[col];
                if constexpr (EPI == 0) {
                    int w = row / 49, p = row - w * 49;
                    int which = col >> 8, h = (col >> 5) & 7, d = col & 31;
                    size_t th = (size_t)(w * 8 + h);
                    if (which == 0)
                        o_q[th * 1568 + p * 32 + d] = f2b(v * SCALE_Q);
                    else if (which == 1)
                        o_k[th * 1568 + p * 32 + d] = f2b(v);
                    else
                        o_v[th * 1568 + p * 32 + d] = f2b(v);   // p-major, like k
                } else if constexpr (EPI == 1) {
                    int w = row / 49, p = row - w * 49;
                    int b2 = w >> 6, widx = w & 63;
                    int wy = widx >> 3, wx = widx & 7;
                    int py = p / 7, px = p - py * 7;
                    int y = wy * 7 + py + SS_;  if (y >= HH) y -= HH;
                    int xx = wx * 7 + px + SS_; if (xx >= WW) xx -= WW;
                    size_t oi = ((size_t)(b2 * 3136 + y * 56 + xx)) * 256 + col;
                    reinterpret_cast<unsigned short*>(out0)[oi] =
                        f2b(v + reinterpret_cast<const float*>(res)[oi]);
                } else if constexpr (EPI == 2) {
                    reinterpret_cast<unsigned short*>(out0)[(size_t)row * 1024 + col] =
                        f2b(gelu(v));
                } else {
                    size_t oi = (size_t)row * 256 + col;
                    reinterpret_cast<float*>(out0)[oi] =
                        v + b2f(reinterpret_cast<const unsigned short*>(res)[oi]);
                }
            }
        }
    }
}

// ---------------- fused window attention: one wave per (window, head) -------
// v arrives P-MAJOR [49][32] (same as k); staging transposes it into the
// proven d-major XOR-swizzled v_s[32][64] via 8 scalar ds_writes per chunk.
// PV read path unchanged. Pad columns p=49..63 zeroed (P=0 there, but
// 0 * stale-LDS could be NaN).
__global__ __launch_bounds__(256) void attn_kernel(
    const unsigned short* __restrict__ qg, const unsigned short* __restrict__ kgl,
    const unsigned short* __restrict__ vg, const float* __restrict__ rpt,
    unsigned short* __restrict__ out) {
    __shared__ __align__(16) unsigned short sm[4][6144];
    __shared__ unsigned short rpts[169 * 8];
    const int tid = threadIdx.x, wid = tid >> 6, lane = tid & 63;
    for (int i = tid; i < 169 * 8; i += 256) rpts[i] = f2b(rpt[i]);
    const int task = blockIdx.x * 4 + wid;
    const int w = task >> 3, h = task & 7;
    const int widx = w & 63, wy = widx >> 3, wx = widx & 7;
    unsigned short* q_s = sm[wid];
    unsigned short* k_s = sm[wid] + 2048;
    unsigned short* v_s = sm[wid] + 4096;
    unsigned short* p_s = sm[wid];
    const unsigned short* qsrc = qg + (size_t)task * 1568;
    const unsigned short* ksrc = kgl + (size_t)task * 1568;
    const unsigned short* vsrc = vg + (size_t)task * 1568;
    // zero v_s pad region p=48..63 (p=48 re-written by staging below)
    for (int i = lane; i < 512; i += 64) {
        int d = i >> 4, p = 48 + (i & 15);
        v_s[d * 64 + (p ^ ((d & 7) << 3))] = 0;
    }
    for (int c = lane; c < 196; c += 64) {
        int row = c >> 2, kc = c & 3;
        int off = (row * 32 + kc * 8) ^ ((row & 7) << 3);
        *reinterpret_cast<short8*>(q_s + off) =
            *reinterpret_cast<const short8*>(qsrc + c * 8);
        *reinterpret_cast<short8*>(k_s + off) =
            *reinterpret_cast<const short8*>(ksrc + c * 8);
        // v transpose: chunk = 8 consecutive d at fixed p
        short8 vv = *reinterpret_cast<const short8*>(vsrc + c * 8);
        int p = c >> 2, d0 = (c & 3) * 8;
#pragma unroll
        for (int e = 0; e < 8; e++) {
            int d = d0 + e;
            v_s[d * 64 + (p ^ ((d & 7) << 3))] = (unsigned short)vv[e];
        }
    }
    __syncthreads();

    const int lr = lane & 15, kg = lane >> 4;
    short8 af[4], bf[4];
#pragma unroll
    for (int mf = 0; mf < 4; mf++) {
        int r = mf * 16 + lr;
        af[mf] = *reinterpret_cast<const short8*>(
            q_s + ((r * 32 + kg * 8) ^ ((r & 7) << 3)));
    }
#pragma unroll
    for (int nf = 0; nf < 4; nf++) {
        int r = nf * 16 + lr;
        bf[nf] = *reinterpret_cast<const short8*>(
            k_s + ((r * 32 + kg * 8) ^ ((r & 7) << 3)));
    }
    f32x4 s[4][4] = {};
#pragma unroll
    for (int mf = 0; mf < 4; mf++)
#pragma unroll
        for (int nf = 0; nf < 4; nf++)
            s[mf][nf] = __builtin_amdgcn_mfma_f32_16x16x32_bf16(af[mf], bf[nf],
                                                                s[mf][nf], 0, 0, 0);
#pragma unroll
    for (int mf = 0; mf < 4; mf++) {
#pragma unroll
        for (int j = 0; j < 4; j++) {
            int row = mf * 16 + kg * 4 + j;
            bool rvalid = row < 49;
            int qy = 0, qx = 0, gq = 0;
            if (rvalid) {
                qy = row / 7; qx = row - qy * 7;
                int yi = wy * 7 + qy, xi = wx * 7 + qx;
                gq = ((yi < 49) ? 0 : ((yi < 53) ? 1 : 2)) * 3 +
                     ((xi < 49) ? 0 : ((xi < 53) ? 1 : 2));
            }
            float L[4];
#pragma unroll
            for (int nf = 0; nf < 4; nf++) {
                int col = nf * 16 + lr;
                float val = s[mf][nf][j];
                if (rvalid && col < 49) {
                    int ky = col / 7, kx = col - ky * 7;
                    int yi = wy * 7 + ky, xi = wx * 7 + kx;
                    int gk = ((yi < 49) ? 0 : ((yi < 53) ? 1 : 2)) * 3 +
                             ((xi < 49) ? 0 : ((xi < 53) ? 1 : 2));
                    val += b2f(rpts[((qy - ky + 6) * 13 + (qx - kx + 6)) * 8 + h]);
                    if (gq != gk) val -= 100.0f;
                } else {
                    val = -1e30f;
                }
                L[nf] = val;
            }
            float m = fmaxf(fmaxf(L[0], L[1]), fmaxf(L[2], L[3]));
#pragma unroll
            for (int t2 = 1; t2 < 16; t2 <<= 1) m = fmaxf(m, __shfl_xor(m, t2));
            float P[4], psum = 0.f;
#pragma unroll
            for (int nf = 0; nf < 4; nf++) {
                P[nf] = __expf(L[nf] - m);
                psum += P[nf];
            }
#pragma unroll
            for (int t2 = 1; t2 < 16; t2 <<= 1) psum += __shfl_xor(psum, t2);
            float inv = 1.0f / psum;
#pragma unroll
            for (int nf = 0; nf < 4; nf++) {
                int col = nf * 16 + lr;
                p_s[(row * 64 + col) ^ ((row & 7) << 3)] = f2b(P[nf] * inv);
            }
        }
    }
    f32x4 o[4][2] = {};
#pragma unroll
    for (int ks = 0; ks < 2; ks++) {
        short8 pa[4], vb[2];
#pragma unroll
        for (int mf = 0; mf < 4; mf++) {
            int r = mf * 16 + lr;
            pa[mf] = *reinterpret_cast<const short8*>(
                p_s + ((r * 64 + ks * 32 + kg * 8) ^ ((r & 7) << 3)));
        }
#pragma unroll
        for (int nf = 0; nf < 2; nf++) {
            int d = nf * 16 + lr;
            vb[nf] = *reinterpret_cast<const short8*>(
                v_s + ((d * 64 + ks * 32 + kg * 8) ^ ((d & 7) << 3)));
        }
#pragma unroll
        for (int mf = 0; mf < 4; mf++)
#pragma unroll
            for (int nf = 0; nf < 2; nf++)
                o[mf][nf] = __builtin_amdgcn_mfma_f32_16x16x32_bf16(
                    pa[mf], vb[nf], o[mf][nf], 0, 0, 0);
    }
#pragma unroll
    for (int mf = 0; mf < 4; mf++) {
#pragma unroll
        for (int j = 0; j < 4; j++) {
            int row = mf * 16 + kg * 4 + j;
            if (row < 49) {
#pragma unroll
                for (int nf = 0; nf < 2; nf++) {
                    int d = nf * 16 + lr;
                    out[((size_t)w * 49 + row) * 256 + h * 32 + d] =
                        f2b(o[mf][nf][j]);
                }
            }
        }
    }
}

// ---------------- launcher --------------------------------------------------
extern "C" void kernel_launch(void* const* d_in, const int* in_sizes, int n_in,
                              void* d_out, int out_size, void* d_ws,
                              size_t ws_size, hipStream_t stream) {
    const float* x     = (const float*)d_in[0];
    const float* g1    = (const float*)d_in[1];
    const float* be1   = (const float*)d_in[2];
    const float* wqkv  = (const float*)d_in[3];
    const float* bqkv  = (const float*)d_in[4];
    const float* rpt   = (const float*)d_in[5];
    const float* wproj = (const float*)d_in[6];
    const float* bproj = (const float*)d_in[7];
    const float* g2    = (const float*)d_in[8];
    const float* be2   = (const float*)d_in[9];
    const float* wfc1  = (const float*)d_in[10];
    const float* bfc1  = (const float*)d_in[11];
    const float* wfc2  = (const float*)d_in[12];
    const float* bfc2  = (const float*)d_in[13];
    float* out = (float*)d_out;
    char* ws = (char*)d_ws;

    unsigned short* hb  = (unsigned short*)(ws);              // 25,690,112 B
    unsigned short* qg  = (unsigned short*)(ws + 25690112);   // 25,690,112
    unsigned short* kgl = (unsigned short*)(ws + 51380224);   // 25,690,112
    unsigned short* vg  = (unsigned short*)(ws + 77070336);   // 25,690,112 used
    unsigned short* x2b = (unsigned short*)(ws + 110624768);  // 25,690,112 (bf16)
    unsigned short* h2  = (unsigned short*)(ws + 162004992);  // 25,690,112
    unsigned short* wT  = (unsigned short*)(ws + 187695104);  // 1,572,864
    unsigned short* wqkvT = wT;
    unsigned short* wprojT = wT + 196608;
    unsigned short* wfc1T  = wT + 262144;
    unsigned short* wfc2T  = wT + 524288;
    unsigned short* a1 = (unsigned short*)ws;  // aliases dead hb/q/k/v

    wconv_kernel<<<(256 * 768 + 255) / 256, 256, 0, stream>>>(wqkv, wqkvT, 256, 768);
    wconv_kernel<<<(256 * 256 + 255) / 256, 256, 0, stream>>>(wproj, wprojT, 256, 256);
    wconv_kernel<<<(256 * 1024 + 255) / 256, 256, 0, stream>>>(wfc1, wfc1T, 256, 1024);
    wconv_kernel<<<(1024 * 256 + 255) / 256, 256, 0, stream>>>(wfc2, wfc2T, 1024, 256);

    ln_kernel<1, float><<<12544, 256, 0, stream>>>(x, g1, be1, hb);
    gemm_kernel<256, 0><<<dim3(6, 392), 256, 0, stream>>>(
        hb, wqkvT, bqkv, nullptr, nullptr, qg, kgl, vg);
    attn_kernel<<<2048, 256, 0, stream>>>(qg, kgl, vg, rpt, hb);
    gemm_kernel<256, 1><<<dim3(2, 392), 256, 0, stream>>>(
        hb, wprojT, bproj, x2b, x, nullptr, nullptr, nullptr);
    ln_kernel<0, unsigned short><<<12544, 256, 0, stream>>>(x2b, g2, be2, h2);
    gemm_kernel<256, 2><<<dim3(8, 392), 256, 0, stream>>>(
        h2, wfc1T, bfc1, a1, nullptr, nullptr, nullptr, nullptr);
    gemm_kernel<1024, 3><<<dim3(2, 392), 256, 0, stream>>>(
        a1, wfc2T, bfc2, out, x2b, nullptr, nullptr, nullptr);
}